// Round 1
// baseline (912.541 us; speedup 1.0000x reference)
//
#include <hip/hip_runtime.h>
#include <hip/hip_bf16.h>
#include <math.h>
#include <stdint.h>

// ---------- constants ----------
#define C_ 384
#define TOKENS 50176          // B*H*W = 16*56*56 = 16*64*49

typedef __bf16 bf16;
typedef __bf16 bf16x8 __attribute__((ext_vector_type(8)));
typedef float  f32x4  __attribute__((ext_vector_type(4)));

__device__ __forceinline__ float b2f(bf16 x) { return (float)x; }
__device__ __forceinline__ bf16  f2b(float x) { return (bf16)x; }

// async global->LDS, 16 bytes per lane. LDS dest must be wave-uniform base + lane*16.
__device__ __forceinline__ void gld_lds16(const bf16* g, bf16* l) {
    __builtin_amdgcn_global_load_lds(
        (const __attribute__((address_space(1))) void*)g,
        (__attribute__((address_space(3))) void*)l, 16, 0, 0);
}

// ---------- K0: weight convert+transpose: in f32 [K][N] -> out bf16 [N][K] ----------
__global__ void wtrans_kernel(const float* __restrict__ in, bf16* __restrict__ out,
                              int K, int N) {
    int idx = blockIdx.x * 256 + threadIdx.x;
    if (idx >= K * N) return;
    int n = idx / K, k = idx % K;
    out[idx] = f2b(in[(size_t)k * N + n]);
}

// ---------- K1: LN1 + roll(-3,-3) + window partition. x BCHW f32 -> xw [50176][384] bf16 ----------
__global__ __launch_bounds__(256) void ln1_gather_kernel(
    const float* __restrict__ x, const float* __restrict__ g,
    const float* __restrict__ bt, bf16* __restrict__ xw) {
    int wave = threadIdx.x >> 6, lane = threadIdx.x & 63;
    int T = blockIdx.x * 4 + wave;
    int wi = T / 49, n = T % 49;
    int b = wi >> 6, w64 = wi & 63;
    int bh = w64 >> 3, bw = w64 & 7;
    int hs = bh * 7 + n / 7 + 3; if (hs >= 56) hs -= 56;
    int wsd = bw * 7 + n % 7 + 3; if (wsd >= 56) wsd -= 56;
    const float* xp = x + (size_t)b * C_ * 3136 + hs * 56 + wsd;
    float v[6];
    #pragma unroll
    for (int k = 0; k < 6; k++) v[k] = xp[(size_t)(lane + k * 64) * 3136];
    float s = v[0] + v[1] + v[2] + v[3] + v[4] + v[5];
    #pragma unroll
    for (int m = 32; m; m >>= 1) s += __shfl_xor(s, m);
    float mu = s * (1.0f / 384.0f);
    float s2 = 0.f;
    #pragma unroll
    for (int k = 0; k < 6; k++) { float d = v[k] - mu; s2 += d * d; }
    #pragma unroll
    for (int m = 32; m; m >>= 1) s2 += __shfl_xor(s2, m);
    float rstd = rsqrtf(s2 * (1.0f / 384.0f) + 1e-5f);
    bf16* op = xw + (size_t)T * 384;
    #pragma unroll
    for (int k = 0; k < 6; k++) {
        int c = lane + k * 64;
        op[c] = f2b((v[k] - mu) * rstd * g[c] + bt[c]);
    }
}

// ---------- GEMM: C[M][N] = A[M][K] @ Wt[N][K]^T + bias, 128x128 tile, BK=32 ----------
enum { EPI_NONE = 0, EPI_GELU = 1, EPI_PROJ = 2, EPI_FC2 = 3 };

template <int EPI>
__global__ __launch_bounds__(256) void gemm_kernel(
    const bf16* __restrict__ A, const bf16* __restrict__ Wt,
    const float* __restrict__ bias, bf16* __restrict__ Cout,
    int Kdim, int Ndim,
    const float* __restrict__ resx,   // EPI_PROJ: x in BCHW f32
    const bf16* __restrict__ resb) {  // EPI_FC2 : x2 token-major bf16
    __shared__ __align__(16) bf16 As[128 * 32];
    __shared__ __align__(16) bf16 Bs[128 * 32];
    int t = threadIdx.x;
    int m0 = blockIdx.x * 128, n0 = blockIdx.y * 128;
    int lane = t & 63, wave = t >> 6;
    int wr = wave >> 1, wc = wave & 1;
    int quad = lane >> 4, lm = lane & 15;
    f32x4 acc[4][4] = {};

    int c1 = t, c2 = t + 256;
    const bf16* ga1 = A + (size_t)(m0 + (c1 >> 2)) * Kdim + (c1 & 3) * 8;
    const bf16* ga2 = A + (size_t)(m0 + (c2 >> 2)) * Kdim + (c2 & 3) * 8;
    const bf16* gb1 = Wt + (size_t)(n0 + (c1 >> 2)) * Kdim + (c1 & 3) * 8;
    const bf16* gb2 = Wt + (size_t)(n0 + (c2 >> 2)) * Kdim + (c2 & 3) * 8;
    bf16* la1 = As + c1 * 8; bf16* la2 = As + c2 * 8;
    bf16* lb1 = Bs + c1 * 8; bf16* lb2 = Bs + c2 * 8;

    for (int k0 = 0; k0 < Kdim; k0 += 32) {
        gld_lds16(ga1 + k0, la1);
        gld_lds16(ga2 + k0, la2);
        gld_lds16(gb1 + k0, lb1);
        gld_lds16(gb2 + k0, lb2);
        __syncthreads();
        bf16x8 af[4], bfr[4];
        #pragma unroll
        for (int i = 0; i < 4; i++)
            af[i] = *(const bf16x8*)(As + (wr * 64 + i * 16 + lm) * 32 + quad * 8);
        #pragma unroll
        for (int j = 0; j < 4; j++)
            bfr[j] = *(const bf16x8*)(Bs + (wc * 64 + j * 16 + lm) * 32 + quad * 8);
        #pragma unroll
        for (int i = 0; i < 4; i++)
            #pragma unroll
            for (int j = 0; j < 4; j++)
                acc[i][j] = __builtin_amdgcn_mfma_f32_16x16x32_bf16(af[i], bfr[j], acc[i][j], 0, 0, 0);
        __syncthreads();
    }

    int col[4]; float bv[4];
    #pragma unroll
    for (int j = 0; j < 4; j++) { col[j] = n0 + wc * 64 + j * 16 + lm; bv[j] = bias[col[j]]; }
    #pragma unroll
    for (int i = 0; i < 4; i++) {
        #pragma unroll
        for (int r = 0; r < 4; r++) {
            int row = m0 + wr * 64 + i * 16 + quad * 4 + r;
            size_t resbase = 0;
            if (EPI == EPI_PROJ) {
                int wi = row / 49, n = row % 49;
                int b = wi >> 6, w64 = wi & 63;
                int bh = w64 >> 3, bw = w64 & 7;
                int hs = bh * 7 + n / 7 + 3; if (hs >= 56) hs -= 56;
                int wsd = bw * 7 + n % 7 + 3; if (wsd >= 56) wsd -= 56;
                resbase = (size_t)b * C_ * 3136 + hs * 56 + wsd;
            }
            #pragma unroll
            for (int j = 0; j < 4; j++) {
                float v = acc[i][j][r] + bv[j];
                if (EPI == EPI_GELU) v = 0.5f * v * (1.0f + erff(v * 0.70710678118f));
                if (EPI == EPI_PROJ) v += resx[resbase + (size_t)col[j] * 3136];
                if (EPI == EPI_FC2)  v += b2f(resb[(size_t)row * 384 + col[j]]);
                Cout[(size_t)row * Ndim + col[j]] = f2b(v);
            }
        }
    }
}

// ---------- K3: windowed attention. one block per (window, head) ----------
__global__ __launch_bounds__(256) void attn_kernel(const bf16* __restrict__ qkv,
                                                   bf16* __restrict__ aout) {
    __shared__ float qs[49 * 33], ks[49 * 33], vs[49 * 33];
    __shared__ float S[49 * 49];
    __shared__ float linv[49];
    __shared__ int reg_[49];
    int t = threadIdx.x;
    int wi = blockIdx.x / 12, h = blockIdx.x % 12;
    const bf16* base = qkv + (size_t)wi * 49 * 1152 + h * 32;
    for (int idx = t; idx < 1568; idx += 256) {
        int n = idx >> 5, d = idx & 31;
        const bf16* rp = base + (size_t)n * 1152;
        qs[n * 33 + d] = b2f(rp[d]) * 0.17677669529663687f;  // 1/sqrt(32)
        ks[n * 33 + d] = b2f(rp[384 + d]);
        vs[n * 33 + d] = b2f(rp[768 + d]);
    }
    if (t < 49) {
        int w64 = wi & 63;
        int bh = w64 >> 3, bw = w64 & 7;
        int hh = bh * 7 + t / 7, ww = bw * 7 + t % 7;
        int fh = hh < 49 ? 0 : (hh < 53 ? 1 : 2);
        int fw = ww < 49 ? 0 : (ww < 53 ? 1 : 2);
        reg_[t] = fh * 3 + fw;
    }
    __syncthreads();
    for (int e = t; e < 2401; e += 256) {
        int i = e / 49, j = e % 49;
        float s = 0.f;
        #pragma unroll
        for (int d = 0; d < 32; d++) s += qs[i * 33 + d] * ks[j * 33 + d];
        if (reg_[i] != reg_[j]) s -= 100.0f;
        S[e] = s;
    }
    __syncthreads();
    if (t < 49) {
        float m = -1e30f;
        for (int j = 0; j < 49; j++) m = fmaxf(m, S[t * 49 + j]);
        float l = 0.f;
        for (int j = 0; j < 49; j++) { float e = __expf(S[t * 49 + j] - m); S[t * 49 + j] = e; l += e; }
        linv[t] = 1.0f / l;
    }
    __syncthreads();
    for (int e = t; e < 1568; e += 256) {
        int i = e >> 5, d = e & 31;
        float o = 0.f;
        for (int m = 0; m < 49; m++) o += S[i * 49 + m] * vs[m * 33 + d];
        aout[((size_t)(wi * 49 + i)) * 384 + h * 32 + d] = f2b(o * linv[i]);
    }
}

// ---------- K5: LN2 on token-major bf16 ----------
__global__ __launch_bounds__(256) void ln2_kernel(const bf16* __restrict__ x2,
                                                  const float* __restrict__ g,
                                                  const float* __restrict__ bt,
                                                  bf16* __restrict__ x2n) {
    int wave = threadIdx.x >> 6, lane = threadIdx.x & 63;
    int T = blockIdx.x * 4 + wave;
    const bf16* xp = x2 + (size_t)T * 384;
    float v[6];
    #pragma unroll
    for (int k = 0; k < 6; k++) v[k] = b2f(xp[lane + k * 64]);
    float s = v[0] + v[1] + v[2] + v[3] + v[4] + v[5];
    #pragma unroll
    for (int m = 32; m; m >>= 1) s += __shfl_xor(s, m);
    float mu = s * (1.0f / 384.0f);
    float s2 = 0.f;
    #pragma unroll
    for (int k = 0; k < 6; k++) { float d = v[k] - mu; s2 += d * d; }
    #pragma unroll
    for (int m = 32; m; m >>= 1) s2 += __shfl_xor(s2, m);
    float rstd = rsqrtf(s2 * (1.0f / 384.0f) + 1e-5f);
    bf16* op = x2n + (size_t)T * 384;
    #pragma unroll
    for (int k = 0; k < 6; k++) {
        int c = lane + k * 64;
        op[c] = f2b((v[k] - mu) * rstd * g[c] + bt[c]);
    }
}

// ---------- K8: window reverse + unshift + transpose to BCHW f32 ----------
__global__ __launch_bounds__(256) void untile_kernel(const bf16* __restrict__ otok,
                                                     float* __restrict__ out) {
    __shared__ float tile[56 * 65];
    int t = threadIdx.x;
    int b = blockIdx.x / 336;       // 56*6
    int rem = blockIdx.x % 336;
    int h = rem / 6;
    int c0 = (rem % 6) * 64;
    int hs = h + 53; if (hs >= 56) hs -= 56;
    int bh = hs / 7, th = hs % 7;
    #pragma unroll
    for (int pass = 0; pass < 14; pass++) {
        int w = pass * 4 + (t >> 6);
        int c = t & 63;
        int wsd = w + 53; if (wsd >= 56) wsd -= 56;
        int T = (b * 64 + bh * 8 + wsd / 7) * 49 + th * 7 + wsd % 7;
        tile[w * 65 + c] = b2f(otok[(size_t)T * 384 + c0 + c]);
    }
    __syncthreads();
    #pragma unroll
    for (int pass = 0; pass < 14; pass++) {
        int idx = pass * 256 + t;
        int c = idx / 56, w = idx % 56;
        out[((size_t)(b * 384 + c0 + c)) * 3136 + h * 56 + w] = tile[w * 65 + c];
    }
}

// ---------- launcher ----------
extern "C" void kernel_launch(void* const* d_in, const int* in_sizes, int n_in,
                              void* d_out, int out_size, void* d_ws, size_t ws_size,
                              hipStream_t stream) {
    (void)in_sizes; (void)n_in; (void)out_size; (void)ws_size;
    const float* x      = (const float*)d_in[0];
    const float* n1g    = (const float*)d_in[1];
    const float* n1b    = (const float*)d_in[2];
    const float* qkv_w  = (const float*)d_in[3];
    const float* qkv_b  = (const float*)d_in[4];
    const float* proj_w = (const float*)d_in[5];
    const float* proj_b = (const float*)d_in[6];
    const float* n2g    = (const float*)d_in[7];
    const float* n2b    = (const float*)d_in[8];
    const float* fc1_w  = (const float*)d_in[9];
    const float* fc1_b  = (const float*)d_in[10];
    const float* fc2_w  = (const float*)d_in[11];
    const float* fc2_b  = (const float*)d_in[12];
    float* out = (float*)d_out;
    char* ws = (char*)d_ws;

    bf16* qkv_wT = (bf16*)(ws + 0);          // 884736 B
    bf16* proj_wT = (bf16*)(ws + 884736);    // 294912 B
    bf16* fc1_wT = (bf16*)(ws + 1179648);    // 1179648 B
    bf16* fc2_wT = (bf16*)(ws + 2359296);    // 1179648 B
    bf16* xw   = (bf16*)(ws + 4194304);      // 38535168 B
    bf16* qkvb = (bf16*)(ws + 42729472);     // 115605504 B
    bf16* attn = (bf16*)(ws + 158334976);    // 38535168 B
    bf16* x2   = (bf16*)(ws + 4194304);      // alias xw (dead)
    bf16* x2n  = (bf16*)(ws + 42729472);     // alias qkv (dead)
    bf16* h1   = (bf16*)(ws + 81264640);     // 154140672 B (overlaps dead attn)
    bf16* otok = (bf16*)(ws + 235405312);    // 38535168 B  (peak ws = 274 MB)

    wtrans_kernel<<<(384 * 1152 + 255) / 256, 256, 0, stream>>>(qkv_w, qkv_wT, 384, 1152);
    wtrans_kernel<<<(384 * 384 + 255) / 256, 256, 0, stream>>>(proj_w, proj_wT, 384, 384);
    wtrans_kernel<<<(384 * 1536 + 255) / 256, 256, 0, stream>>>(fc1_w, fc1_wT, 384, 1536);
    wtrans_kernel<<<(1536 * 384 + 255) / 256, 256, 0, stream>>>(fc2_w, fc2_wT, 1536, 384);

    ln1_gather_kernel<<<TOKENS / 4, 256, 0, stream>>>(x, n1g, n1b, xw);

    gemm_kernel<EPI_NONE><<<dim3(392, 9), 256, 0, stream>>>(
        xw, qkv_wT, qkv_b, qkvb, 384, 1152, nullptr, nullptr);

    attn_kernel<<<12288, 256, 0, stream>>>(qkvb, attn);

    gemm_kernel<EPI_PROJ><<<dim3(392, 3), 256, 0, stream>>>(
        attn, proj_wT, proj_b, x2, 384, 384, x, nullptr);

    ln2_kernel<<<TOKENS / 4, 256, 0, stream>>>(x2, n2g, n2b, x2n);

    gemm_kernel<EPI_GELU><<<dim3(392, 12), 256, 0, stream>>>(
        x2n, fc1_wT, fc1_b, h1, 384, 1536, nullptr, nullptr);

    gemm_kernel<EPI_FC2><<<dim3(392, 3), 256, 0, stream>>>(
        h1, fc2_wT, fc2_b, otok, 1536, 384, nullptr, x2);

    untile_kernel<<<16 * 336, 256, 0, stream>>>(otok, out);
}

// Round 2
// 747.977 us; speedup vs baseline: 1.2200x; 1.2200x over previous
//
#include <hip/hip_runtime.h>
#include <hip/hip_bf16.h>
#include <math.h>
#include <stdint.h>

// ---------- constants ----------
#define C_ 384
#define TOKENS 50176          // B*H*W = 16*56*56 = 16*64*49

typedef __bf16 bf16;
typedef __bf16 bf16x8 __attribute__((ext_vector_type(8)));
typedef float  f32x4  __attribute__((ext_vector_type(4)));

__device__ __forceinline__ float b2f(bf16 x) { return (float)x; }
__device__ __forceinline__ bf16  f2b(float x) { return (bf16)x; }

// async global->LDS, 16 bytes per lane. LDS dest must be wave-uniform base + lane*16.
__device__ __forceinline__ void gld_lds16(const bf16* g, bf16* l) {
    __builtin_amdgcn_global_load_lds(
        (const __attribute__((address_space(1))) void*)g,
        (__attribute__((address_space(3))) void*)l, 16, 0, 0);
}

// ---------- K0: weight convert+transpose: in f32 [K][N] -> out bf16 [N][K] ----------
__global__ void wtrans_kernel(const float* __restrict__ in, bf16* __restrict__ out,
                              int K, int N) {
    int idx = blockIdx.x * 256 + threadIdx.x;
    if (idx >= K * N) return;
    int n = idx / K, k = idx % K;
    out[idx] = f2b(in[(size_t)k * N + n]);
}

// ---------- K1: LN1 + roll(-3,-3) + window partition. x BCHW f32 -> xw [50176][384] bf16 ----------
__global__ __launch_bounds__(256) void ln1_gather_kernel(
    const float* __restrict__ x, const float* __restrict__ g,
    const float* __restrict__ bt, bf16* __restrict__ xw) {
    int wave = threadIdx.x >> 6, lane = threadIdx.x & 63;
    int T = blockIdx.x * 4 + wave;
    int wi = T / 49, n = T % 49;
    int b = wi >> 6, w64 = wi & 63;
    int bh = w64 >> 3, bw = w64 & 7;
    int hs = bh * 7 + n / 7 + 3; if (hs >= 56) hs -= 56;
    int wsd = bw * 7 + n % 7 + 3; if (wsd >= 56) wsd -= 56;
    const float* xp = x + (size_t)b * C_ * 3136 + hs * 56 + wsd;
    float v[6];
    #pragma unroll
    for (int k = 0; k < 6; k++) v[k] = xp[(size_t)(lane + k * 64) * 3136];
    float s = v[0] + v[1] + v[2] + v[3] + v[4] + v[5];
    #pragma unroll
    for (int m = 32; m; m >>= 1) s += __shfl_xor(s, m);
    float mu = s * (1.0f / 384.0f);
    float s2 = 0.f;
    #pragma unroll
    for (int k = 0; k < 6; k++) { float d = v[k] - mu; s2 += d * d; }
    #pragma unroll
    for (int m = 32; m; m >>= 1) s2 += __shfl_xor(s2, m);
    float rstd = rsqrtf(s2 * (1.0f / 384.0f) + 1e-5f);
    bf16* op = xw + (size_t)T * 384;
    #pragma unroll
    for (int k = 0; k < 6; k++) {
        int c = lane + k * 64;
        op[c] = f2b((v[k] - mu) * rstd * g[c] + bt[c]);
    }
}

// ---------- GEMM: C[M][N] = A[M][K] @ Wt[N][K]^T + bias, 128x128 tile, BK=32 ----------
enum { EPI_NONE = 0, EPI_GELU = 1, EPI_PROJ = 2, EPI_FC2 = 3 };

template <int EPI>
__global__ __launch_bounds__(256) void gemm_kernel(
    const bf16* __restrict__ A, const bf16* __restrict__ Wt,
    const float* __restrict__ bias, bf16* __restrict__ Cout,
    int Kdim, int Ndim,
    const float* __restrict__ resx,   // EPI_PROJ: x in BCHW f32
    const bf16* __restrict__ resb) {  // EPI_FC2 : x2 token-major bf16
    __shared__ __align__(16) bf16 As[128 * 32];
    __shared__ __align__(16) bf16 Bs[128 * 32];
    int t = threadIdx.x;
    int m0 = blockIdx.x * 128, n0 = blockIdx.y * 128;
    int lane = t & 63, wave = t >> 6;
    int wr = wave >> 1, wc = wave & 1;
    int quad = lane >> 4, lm = lane & 15;
    f32x4 acc[4][4] = {};

    int c1 = t, c2 = t + 256;
    const bf16* ga1 = A + (size_t)(m0 + (c1 >> 2)) * Kdim + (c1 & 3) * 8;
    const bf16* ga2 = A + (size_t)(m0 + (c2 >> 2)) * Kdim + (c2 & 3) * 8;
    const bf16* gb1 = Wt + (size_t)(n0 + (c1 >> 2)) * Kdim + (c1 & 3) * 8;
    const bf16* gb2 = Wt + (size_t)(n0 + (c2 >> 2)) * Kdim + (c2 & 3) * 8;
    bf16* la1 = As + c1 * 8; bf16* la2 = As + c2 * 8;
    bf16* lb1 = Bs + c1 * 8; bf16* lb2 = Bs + c2 * 8;

    for (int k0 = 0; k0 < Kdim; k0 += 32) {
        gld_lds16(ga1 + k0, la1);
        gld_lds16(ga2 + k0, la2);
        gld_lds16(gb1 + k0, lb1);
        gld_lds16(gb2 + k0, lb2);
        __syncthreads();
        bf16x8 af[4], bfr[4];
        #pragma unroll
        for (int i = 0; i < 4; i++)
            af[i] = *(const bf16x8*)(As + (wr * 64 + i * 16 + lm) * 32 + quad * 8);
        #pragma unroll
        for (int j = 0; j < 4; j++)
            bfr[j] = *(const bf16x8*)(Bs + (wc * 64 + j * 16 + lm) * 32 + quad * 8);
        #pragma unroll
        for (int i = 0; i < 4; i++)
            #pragma unroll
            for (int j = 0; j < 4; j++)
                acc[i][j] = __builtin_amdgcn_mfma_f32_16x16x32_bf16(af[i], bfr[j], acc[i][j], 0, 0, 0);
        __syncthreads();
    }

    int col[4]; float bv[4];
    #pragma unroll
    for (int j = 0; j < 4; j++) { col[j] = n0 + wc * 64 + j * 16 + lm; bv[j] = bias[col[j]]; }
    #pragma unroll
    for (int i = 0; i < 4; i++) {
        #pragma unroll
        for (int r = 0; r < 4; r++) {
            int row = m0 + wr * 64 + i * 16 + quad * 4 + r;
            size_t resbase = 0;
            if (EPI == EPI_PROJ) {
                int wi = row / 49, n = row % 49;
                int b = wi >> 6, w64 = wi & 63;
                int bh = w64 >> 3, bw = w64 & 7;
                int hs = bh * 7 + n / 7 + 3; if (hs >= 56) hs -= 56;
                int wsd = bw * 7 + n % 7 + 3; if (wsd >= 56) wsd -= 56;
                resbase = (size_t)b * C_ * 3136 + hs * 56 + wsd;
            }
            #pragma unroll
            for (int j = 0; j < 4; j++) {
                float v = acc[i][j][r] + bv[j];
                if (EPI == EPI_GELU) v = 0.5f * v * (1.0f + erff(v * 0.70710678118f));
                if (EPI == EPI_PROJ) v += resx[resbase + (size_t)col[j] * 3136];
                if (EPI == EPI_FC2)  v += b2f(resb[(size_t)row * 384 + col[j]]);
                Cout[(size_t)row * Ndim + col[j]] = f2b(v);
            }
        }
    }
}

// ---------- K3: MFMA windowed attention. one wave-block per (window, head) ----------
// S = Q K^T via mfma_16x16x32 (M=N=64 padded, K=32); softmax in registers on the
// C-layout (col=lane&15, row=quad*4+reg) with shfl_xor butterflies over the
// 16-lane quad group; P -> LDS (stride 72, 2-way-conflict-free) -> A-frags;
// V B-frags as scalar global loads (L1-resident). P cols >=49 are exactly 0,
// so padded/clamped V rows contribute nothing.
__global__ __launch_bounds__(64) void attn_mfma_kernel(const bf16* __restrict__ qkv,
                                                       bf16* __restrict__ aout) {
    __shared__ __align__(16) bf16 pbuf[64 * 72];
    __shared__ int reg_[64];
    int l = threadIdx.x;
    int wi = blockIdx.x / 12, h = blockIdx.x % 12;
    int i16 = l & 15, quad = l >> 4;

    // region labels for the shifted-window mask (token space of this window)
    {
        int tok = l < 49 ? l : 48;
        int w64 = wi & 63;
        int bh = w64 >> 3, bw = w64 & 7;
        int hh = bh * 7 + tok / 7, ww = bw * 7 + tok % 7;
        int fh = hh < 49 ? 0 : (hh < 53 ? 1 : 2);
        int fw = ww < 49 ? 0 : (ww < 53 ? 1 : 2);
        reg_[l] = fh * 3 + fw;
    }
    __syncthreads();

    const bf16* qbase = qkv + (size_t)wi * 49 * 1152 + h * 32;

    // ---- S = Q @ K^T ----
    f32x4 s_[4][4] = {};   // [mi][nt], C-layout
    bf16x8 af[4], bfr[4];
    #pragma unroll
    for (int mi = 0; mi < 4; mi++) {
        int m = mi * 16 + i16; if (m > 48) m = 48;
        af[mi] = *(const bf16x8*)(qbase + (size_t)m * 1152 + quad * 8);
    }
    #pragma unroll
    for (int nt = 0; nt < 4; nt++) {
        int n = nt * 16 + i16; if (n > 48) n = 48;
        bfr[nt] = *(const bf16x8*)(qbase + 384 + (size_t)n * 1152 + quad * 8);
    }
    #pragma unroll
    for (int mi = 0; mi < 4; mi++)
        #pragma unroll
        for (int nt = 0; nt < 4; nt++)
            s_[mi][nt] = __builtin_amdgcn_mfma_f32_16x16x32_bf16(af[mi], bfr[nt], s_[mi][nt], 0, 0, 0);

    // column region labels (col = nt*16 + i16), col>48 handled by -inf anyway
    int creg[4];
    #pragma unroll
    for (int nt = 0; nt < 4; nt++) {
        int c = nt * 16 + i16; if (c > 48) c = 48;
        creg[nt] = reg_[c];
    }

    // ---- mask + softmax (per row, across 16 lanes x 4 col-tiles) ----
    const float scale = 0.17677669529663687f;  // 1/sqrt(32)
    #pragma unroll
    for (int mi = 0; mi < 4; mi++) {
        #pragma unroll
        for (int r = 0; r < 4; r++) {
            int row = mi * 16 + quad * 4 + r;
            int rreg = reg_[row];
            float v[4]; float mx = -1e30f;
            #pragma unroll
            for (int nt = 0; nt < 4; nt++) {
                int c = nt * 16 + i16;
                float x = s_[mi][nt][r] * scale;
                if (c > 48) x = -1e30f;
                else if (rreg != creg[nt]) x -= 100.0f;
                v[nt] = x; mx = fmaxf(mx, x);
            }
            #pragma unroll
            for (int m = 8; m; m >>= 1) mx = fmaxf(mx, __shfl_xor(mx, m));
            float sum = 0.f;
            #pragma unroll
            for (int nt = 0; nt < 4; nt++) { v[nt] = __expf(v[nt] - mx); sum += v[nt]; }
            #pragma unroll
            for (int m = 8; m; m >>= 1) sum += __shfl_xor(sum, m);
            float inv = 1.0f / sum;
            #pragma unroll
            for (int nt = 0; nt < 4; nt++)
                pbuf[row * 72 + nt * 16 + i16] = f2b(v[nt] * inv);
        }
    }
    __syncthreads();

    // ---- O = P @ V ----
    f32x4 o_[4][2] = {};
    const bf16* vbase = qkv + (size_t)wi * 49 * 1152 + 768 + h * 32;
    #pragma unroll
    for (int ks = 0; ks < 2; ks++) {
        bf16x8 pa[4];
        #pragma unroll
        for (int mi = 0; mi < 4; mi++)
            pa[mi] = *(const bf16x8*)(pbuf + (mi * 16 + i16) * 72 + ks * 32 + quad * 8);
        bf16x8 vb[2];
        #pragma unroll
        for (int nt = 0; nt < 2; nt++)
            #pragma unroll
            for (int j = 0; j < 8; j++) {
                int tok = ks * 32 + quad * 8 + j; if (tok > 48) tok = 48;
                vb[nt][j] = vbase[(size_t)tok * 1152 + nt * 16 + i16];
            }
        #pragma unroll
        for (int mi = 0; mi < 4; mi++)
            #pragma unroll
            for (int nt = 0; nt < 2; nt++)
                o_[mi][nt] = __builtin_amdgcn_mfma_f32_16x16x32_bf16(pa[mi], vb[nt], o_[mi][nt], 0, 0, 0);
    }

    // ---- epilogue: write rows < 49 ----
    bf16* obase = aout + (size_t)wi * 49 * 384 + h * 32;
    #pragma unroll
    for (int mi = 0; mi < 4; mi++)
        #pragma unroll
        for (int r = 0; r < 4; r++) {
            int row = mi * 16 + quad * 4 + r;
            if (row < 49) {
                #pragma unroll
                for (int nt = 0; nt < 2; nt++)
                    obase[(size_t)row * 384 + nt * 16 + i16] = f2b(o_[mi][nt][r]);
            }
        }
}

// ---------- K5: LN2 on token-major bf16 ----------
__global__ __launch_bounds__(256) void ln2_kernel(const bf16* __restrict__ x2,
                                                  const float* __restrict__ g,
                                                  const float* __restrict__ bt,
                                                  bf16* __restrict__ x2n) {
    int wave = threadIdx.x >> 6, lane = threadIdx.x & 63;
    int T = blockIdx.x * 4 + wave;
    const bf16* xp = x2 + (size_t)T * 384;
    float v[6];
    #pragma unroll
    for (int k = 0; k < 6; k++) v[k] = b2f(xp[lane + k * 64]);
    float s = v[0] + v[1] + v[2] + v[3] + v[4] + v[5];
    #pragma unroll
    for (int m = 32; m; m >>= 1) s += __shfl_xor(s, m);
    float mu = s * (1.0f / 384.0f);
    float s2 = 0.f;
    #pragma unroll
    for (int k = 0; k < 6; k++) { float d = v[k] - mu; s2 += d * d; }
    #pragma unroll
    for (int m = 32; m; m >>= 1) s2 += __shfl_xor(s2, m);
    float rstd = rsqrtf(s2 * (1.0f / 384.0f) + 1e-5f);
    bf16* op = x2n + (size_t)T * 384;
    #pragma unroll
    for (int k = 0; k < 6; k++) {
        int c = lane + k * 64;
        op[c] = f2b((v[k] - mu) * rstd * g[c] + bt[c]);
    }
}

// ---------- K8: window reverse + unshift + transpose to BCHW f32 ----------
__global__ __launch_bounds__(256) void untile_kernel(const bf16* __restrict__ otok,
                                                     float* __restrict__ out) {
    __shared__ float tile[56 * 65];
    int t = threadIdx.x;
    int b = blockIdx.x / 336;       // 56*6
    int rem = blockIdx.x % 336;
    int h = rem / 6;
    int c0 = (rem % 6) * 64;
    int hs = h + 53; if (hs >= 56) hs -= 56;
    int bh = hs / 7, th = hs % 7;
    #pragma unroll
    for (int pass = 0; pass < 14; pass++) {
        int w = pass * 4 + (t >> 6);
        int c = t & 63;
        int wsd = w + 53; if (wsd >= 56) wsd -= 56;
        int T = (b * 64 + bh * 8 + wsd / 7) * 49 + th * 7 + wsd % 7;
        tile[w * 65 + c] = b2f(otok[(size_t)T * 384 + c0 + c]);
    }
    __syncthreads();
    #pragma unroll
    for (int pass = 0; pass < 14; pass++) {
        int idx = pass * 256 + t;
        int c = idx / 56, w = idx % 56;
        out[((size_t)(b * 384 + c0 + c)) * 3136 + h * 56 + w] = tile[w * 65 + c];
    }
}

// ---------- launcher ----------
extern "C" void kernel_launch(void* const* d_in, const int* in_sizes, int n_in,
                              void* d_out, int out_size, void* d_ws, size_t ws_size,
                              hipStream_t stream) {
    (void)in_sizes; (void)n_in; (void)out_size; (void)ws_size;
    const float* x      = (const float*)d_in[0];
    const float* n1g    = (const float*)d_in[1];
    const float* n1b    = (const float*)d_in[2];
    const float* qkv_w  = (const float*)d_in[3];
    const float* qkv_b  = (const float*)d_in[4];
    const float* proj_w = (const float*)d_in[5];
    const float* proj_b = (const float*)d_in[6];
    const float* n2g    = (const float*)d_in[7];
    const float* n2b    = (const float*)d_in[8];
    const float* fc1_w  = (const float*)d_in[9];
    const float* fc1_b  = (const float*)d_in[10];
    const float* fc2_w  = (const float*)d_in[11];
    const float* fc2_b  = (const float*)d_in[12];
    float* out = (float*)d_out;
    char* ws = (char*)d_ws;

    bf16* qkv_wT = (bf16*)(ws + 0);          // 884736 B
    bf16* proj_wT = (bf16*)(ws + 884736);    // 294912 B
    bf16* fc1_wT = (bf16*)(ws + 1179648);    // 1179648 B
    bf16* fc2_wT = (bf16*)(ws + 2359296);    // 1179648 B
    bf16* xw   = (bf16*)(ws + 4194304);      // 38535168 B
    bf16* qkvb = (bf16*)(ws + 42729472);     // 115605504 B
    bf16* attn = (bf16*)(ws + 158334976);    // 38535168 B
    bf16* x2   = (bf16*)(ws + 4194304);      // alias xw (dead)
    bf16* x2n  = (bf16*)(ws + 42729472);     // alias qkv (dead)
    bf16* h1   = (bf16*)(ws + 81264640);     // 154140672 B (overlaps dead attn)
    bf16* otok = (bf16*)(ws + 235405312);    // 38535168 B  (peak ws = 274 MB)

    wtrans_kernel<<<(384 * 1152 + 255) / 256, 256, 0, stream>>>(qkv_w, qkv_wT, 384, 1152);
    wtrans_kernel<<<(384 * 384 + 255) / 256, 256, 0, stream>>>(proj_w, proj_wT, 384, 384);
    wtrans_kernel<<<(384 * 1536 + 255) / 256, 256, 0, stream>>>(fc1_w, fc1_wT, 384, 1536);
    wtrans_kernel<<<(1536 * 384 + 255) / 256, 256, 0, stream>>>(fc2_w, fc2_wT, 1536, 384);

    ln1_gather_kernel<<<TOKENS / 4, 256, 0, stream>>>(x, n1g, n1b, xw);

    gemm_kernel<EPI_NONE><<<dim3(392, 9), 256, 0, stream>>>(
        xw, qkv_wT, qkv_b, qkvb, 384, 1152, nullptr, nullptr);

    attn_mfma_kernel<<<12288, 64, 0, stream>>>(qkvb, attn);

    gemm_kernel<EPI_PROJ><<<dim3(392, 3), 256, 0, stream>>>(
        attn, proj_wT, proj_b, x2, 384, 384, x, nullptr);

    ln2_kernel<<<TOKENS / 4, 256, 0, stream>>>(x2, n2g, n2b, x2n);

    gemm_kernel<EPI_GELU><<<dim3(392, 12), 256, 0, stream>>>(
        x2n, fc1_wT, fc1_b, h1, 384, 1536, nullptr, nullptr);

    gemm_kernel<EPI_FC2><<<dim3(392, 3), 256, 0, stream>>>(
        h1, fc2_wT, fc2_b, otok, 1536, 384, nullptr, x2);

    untile_kernel<<<16 * 336, 256, 0, stream>>>(otok, out);
}